// Round 1
// baseline (8272.793 us; speedup 1.0000x reference)
//
#include <hip/hip_runtime.h>

#define SS 2048
#define BATCH 64

typedef short short8 __attribute__((ext_vector_type(8)));
typedef float f32x4 __attribute__((ext_vector_type(4)));
typedef unsigned short u16;

__device__ __forceinline__ u16 f2bf(float f) {
    unsigned int u = __builtin_bit_cast(unsigned int, f);
    u += 0x7fffu + ((u >> 16) & 1u);   // RNE; inputs are finite, no NaN handling needed
    return (u16)(u >> 16);
}
__device__ __forceinline__ float bf2f(u16 h) {
    unsigned int u = ((unsigned int)h) << 16;
    return __builtin_bit_cast(float, u);
}
// tanh(x) = 1 - 2/(exp(2x)+1); exp via v_exp_f32 (2^x). Handles +-inf overflow -> +-1.
__device__ __forceinline__ float fast_tanh(float x) {
    float e = __builtin_amdgcn_exp2f(x * 2.885390081777927f); // 2*log2(e)
    float r = __builtin_amdgcn_rcpf(e + 1.0f);
    return 1.0f - 2.0f * r;
}

// x (B,S,256) f32  ->  xb (S,B,256) bf16   (row r = s*64+b)
__global__ __launch_bounds__(256) void k_conv_x(const float4* __restrict__ x, u16* __restrict__ xb) {
    int idx = blockIdx.x * 256 + threadIdx.x;    // over 64*2048*64 float4s
    float4 v = x[idx];
    int k4 = idx & 63, s = (idx >> 6) & 2047, b = idx >> 17;
    ushort4 o;
    o.x = f2bf(v.x); o.y = f2bf(v.y); o.z = f2bf(v.z); o.w = f2bf(v.w);
    *(ushort4*)(xb + ((s << 6) | b) * 256 + (k4 << 2)) = o;
}

// generic f32 matrix slice -> dense bf16:  dst[r*cnt+c] = W[r*ctot + c0 + c]
__global__ __launch_bounds__(256) void k_conv_w(const float* __restrict__ W, u16* __restrict__ dst,
                                                int ctot, int c0, int lgc, int n) {
    int i = blockIdx.x * 256 + threadIdx.x;
    if (i >= n) return;
    int r = i >> lgc, c = i & ((1 << lgc) - 1);
    dst[i] = f2bf(W[r * ctot + c0 + c]);
}

// pre[m][n] = sum_k A[m][k]*W[n][k] + bias[n], stored bf16. A: M x K bf16 (M=131072), W: 256 x K bf16.
// grid (M/64, 4); block 256 (4 waves). Wave w: rows m0..m0+15, cols n0..n0+63.
__global__ __launch_bounds__(256, 1) void k_proj(const u16* __restrict__ A, const u16* __restrict__ W,
                                                 const float* __restrict__ bias, u16* __restrict__ out, int K) {
    const int w = threadIdx.x >> 6, ln = threadIdx.x & 63, q = ln >> 4, l = ln & 15;
    const int m0 = blockIdx.x * 64 + w * 16;
    const int n0 = blockIdx.y * 64;
    f32x4 acc[4];
#pragma unroll
    for (int u = 0; u < 4; ++u)
#pragma unroll
        for (int r = 0; r < 4; ++r) acc[u][r] = 0.0f;
    const u16* Ap = A + (size_t)(m0 + l) * K + q * 8;
    const u16* Wp = W + (size_t)(n0 + l) * K + q * 8;
    const int nch = K >> 5;
    for (int c = 0; c < nch; ++c) {
        short8 af = *(const short8*)(Ap + c * 32);
#pragma unroll
        for (int u = 0; u < 4; ++u) {
            short8 bf = *(const short8*)(Wp + u * 16 * K + c * 32);
            acc[u] = __builtin_amdgcn_mfma_f32_16x16x32_bf16(af, bf, acc[u], 0, 0, 0);
        }
    }
#pragma unroll
    for (int u = 0; u < 4; ++u) {
        float bia = bias[n0 + u * 16 + l];
#pragma unroll
        for (int r = 0; r < 4; ++r)
            out[(size_t)(m0 + q * 4 + r) * 256 + n0 + u * 16 + l] = f2bf(acc[u][r] + bia);
    }
}

// Recurrence: h_t = tanh(pre[s] + Wh h_{t-1}), orientation C' = Wh * h^T so C/D cols = batch.
// grid 8: dir = blk>>2 (0 fwd, 1 bwd), bc = blk&3 -> batch rows bc*16..+15. block 256 (4 waves).
// Wh held in registers as MFMA A-fragments (128 VGPRs). h exchanged via double-buffered LDS (bf16,
// padded stride 264 -> 2-way bank aliasing only). pre prefetched 1 step ahead. One barrier/step.
template <int FINAL>
__global__ __launch_bounds__(256, 1) void k_recur(const u16* __restrict__ pre_f, const u16* __restrict__ pre_b,
                                                  const u16* __restrict__ wh_f, const u16* __restrict__ wh_b,
                                                  u16* __restrict__ ybf, float* __restrict__ yf) {
    const int dir = blockIdx.x >> 2, bc = blockIdx.x & 3;
    const int w = threadIdx.x >> 6, ln = threadIdx.x & 63, q = ln >> 4, l = ln & 15;
    const int b0 = bc * 16;
    const u16* pre = dir ? pre_b : pre_f;
    const u16* wh  = dir ? wh_b : wh_f;
    const int coloff = dir * 256;
    const int jbase = w * 64;

    __shared__ __align__(16) u16 hbuf[2][16 * 264];

    short8 whf[4][8];   // Wh A-fragments: Wh[jbase+t*16+l][c*32+q*8 ..+7]
#pragma unroll
    for (int t = 0; t < 4; ++t) {
        const u16* wp = wh + (jbase + t * 16 + l) * 256 + q * 8;
#pragma unroll
        for (int c = 0; c < 8; ++c) whf[t][c] = *(const short8*)(wp + c * 32);
    }
    for (int i = threadIdx.x; i < 16 * 264; i += 256) hbuf[0][i] = 0;  // h_0 = 0
    __syncthreads();

    int s = dir ? (SS - 1) : 0;
    const int sstep = dir ? -1 : 1;

    ushort4 pf[2][4];   // pre prefetch double-buffer
    {
        const u16* pp = pre + (size_t)(s * 64 + b0 + l) * 256 + jbase + q * 4;
#pragma unroll
        for (int t = 0; t < 4; ++t) pf[0][t] = *(const ushort4*)(pp + t * 16);
    }

    for (int it = 0; it < SS; ++it) {
        const int cur = it & 1, nxt = cur ^ 1;
        // issue next step's pre loads first (hidden under this step's compute)
        const int sn = (it < SS - 1) ? (s + sstep) : s;
        {
            const u16* pp = pre + (size_t)(sn * 64 + b0 + l) * 256 + jbase + q * 4;
#pragma unroll
            for (int t = 0; t < 4; ++t) pf[nxt][t] = *(const ushort4*)(pp + t * 16);
        }
        f32x4 acc[4];
#pragma unroll
        for (int t = 0; t < 4; ++t) {
            acc[t][0] = bf2f(pf[cur][t].x); acc[t][1] = bf2f(pf[cur][t].y);
            acc[t][2] = bf2f(pf[cur][t].z); acc[t][3] = bf2f(pf[cur][t].w);
        }
        // B-fragments: h[b=l][k = c*32 + q*8 ..+7]
        short8 hf[8];
#pragma unroll
        for (int c = 0; c < 8; ++c) hf[c] = *(const short8*)(&hbuf[cur][l * 264 + c * 32 + q * 8]);
#pragma unroll
        for (int c = 0; c < 8; ++c) {
#pragma unroll
            for (int t = 0; t < 4; ++t)
                acc[t] = __builtin_amdgcn_mfma_f32_16x16x32_bf16(whf[t][c], hf[c], acc[t], 0, 0, 0);
        }
        // tanh, write outputs + next h
#pragma unroll
        for (int t = 0; t < 4; ++t) {
            float v0 = fast_tanh(acc[t][0]), v1 = fast_tanh(acc[t][1]);
            float v2 = fast_tanh(acc[t][2]), v3 = fast_tanh(acc[t][3]);
            ushort4 hv;
            hv.x = f2bf(v0); hv.y = f2bf(v1); hv.z = f2bf(v2); hv.w = f2bf(v3);
            if (FINAL) {
                float4 ov = make_float4(v0, v1, v2, v3);
                *(float4*)(yf + (size_t)(b0 + l) * SS * 512 + (size_t)s * 512 + coloff + jbase + t * 16 + q * 4) = ov;
            } else {
                *(ushort4*)(ybf + ((size_t)s * 64 + b0 + l) * 512 + coloff + jbase + t * 16 + q * 4) = hv;
            }
            *(ushort4*)(&hbuf[nxt][l * 264 + jbase + t * 16 + q * 4]) = hv;
        }
        __syncthreads();
        s += sstep;
    }
}

__global__ __launch_bounds__(256) void k_zero(float* __restrict__ p) {
    p[blockIdx.x * 256 + threadIdx.x] = 0.0f;
}

extern "C" void kernel_launch(void* const* d_in, const int* in_sizes, int n_in,
                              void* d_out, int out_size, void* d_ws, size_t ws_size,
                              hipStream_t stream) {
    const float* x   = (const float*)d_in[0];
    const float* W0f = (const float*)d_in[1];
    const float* b0f = (const float*)d_in[2];
    const float* W0b = (const float*)d_in[3];
    const float* b0b = (const float*)d_in[4];
    const float* W1f = (const float*)d_in[5];
    const float* b1f = (const float*)d_in[6];
    const float* W1b = (const float*)d_in[7];
    const float* b1b = (const float*)d_in[8];
    float* out = (float*)d_out;

    char* ws = (char*)d_ws;
    const size_t MB64 = 64ull << 20;
    u16* xb    = (u16*)(ws);               // 64 MiB: xb (S,B,256) bf16; reused later as pre1f
    u16* pre0f = (u16*)(ws + 1 * MB64);    // 64 MiB: pre0f; reused later as pre1b
    u16* pre0b = (u16*)(ws + 2 * MB64);    // 64 MiB
    u16* y0    = (u16*)(ws + 3 * MB64);    // 128 MiB: y0 (S,B,512) bf16
    u16* wgt   = (u16*)(ws + 5 * MB64);    // ~1.3 MiB of converted weights
    u16 *w0fx = wgt,           *w0fh = wgt + 65536,  *w0bx = wgt + 131072, *w0bh = wgt + 196608;
    u16 *w1fx = wgt + 262144,  *w1fh = wgt + 393216, *w1bx = wgt + 458752, *w1bh = wgt + 589824;
    u16* pre1f = xb;
    u16* pre1b = pre0f;

    k_conv_x<<<32768, 256, 0, stream>>>((const float4*)x, xb);
    k_conv_w<<<256, 256, 0, stream>>>(W0f, w0fx, 512, 0,   8, 65536);
    k_conv_w<<<256, 256, 0, stream>>>(W0f, w0fh, 512, 256, 8, 65536);
    k_conv_w<<<256, 256, 0, stream>>>(W0b, w0bx, 512, 0,   8, 65536);
    k_conv_w<<<256, 256, 0, stream>>>(W0b, w0bh, 512, 256, 8, 65536);
    k_conv_w<<<512, 256, 0, stream>>>(W1f, w1fx, 768, 0,   9, 131072);
    k_conv_w<<<256, 256, 0, stream>>>(W1f, w1fh, 768, 512, 8, 65536);
    k_conv_w<<<512, 256, 0, stream>>>(W1b, w1bx, 768, 0,   9, 131072);
    k_conv_w<<<256, 256, 0, stream>>>(W1b, w1bh, 768, 512, 8, 65536);

    dim3 pg(2048, 4);
    k_proj<<<pg, 256, 0, stream>>>(xb, w0fx, b0f, pre0f, 256);
    k_proj<<<pg, 256, 0, stream>>>(xb, w0bx, b0b, pre0b, 256);
    k_recur<0><<<8, 256, 0, stream>>>(pre0f, pre0b, w0fh, w0bh, y0, nullptr);
    k_proj<<<pg, 256, 0, stream>>>(y0, w1fx, b1f, pre1f, 512);
    k_proj<<<pg, 256, 0, stream>>>(y0, w1bx, b1b, pre1b, 512);
    k_recur<1><<<8, 256, 0, stream>>>(pre1f, pre1b, w1fh, w1bh, nullptr, out);
    k_zero<<<256, 256, 0, stream>>>(out + 67108864);  // hn = zeros(4,64,256)
}

// Round 2
// 5418.952 us; speedup vs baseline: 1.5266x; 1.5266x over previous
//
#include <hip/hip_runtime.h>

#define SS 2048
#define BATCH 64

typedef short short8 __attribute__((ext_vector_type(8)));
typedef float f32x4 __attribute__((ext_vector_type(4)));
typedef unsigned short u16;

__device__ __forceinline__ u16 f2bf(float f) {
    unsigned int u = __builtin_bit_cast(unsigned int, f);
    u += 0x7fffu + ((u >> 16) & 1u);   // RNE; finite inputs
    return (u16)(u >> 16);
}
__device__ __forceinline__ float bf2f(u16 h) {
    unsigned int u = ((unsigned int)h) << 16;
    return __builtin_bit_cast(float, u);
}
// tanh(x) = 1 - 2/(exp(2x)+1); exp via v_exp_f32. Saturates correctly for |x| large.
__device__ __forceinline__ float fast_tanh(float x) {
    float e = __builtin_amdgcn_exp2f(x * 2.885390081777927f); // 2*log2(e)
    float r = __builtin_amdgcn_rcpf(e + 1.0f);
    return 1.0f - 2.0f * r;
}

// x (B,S,256) f32  ->  xb (S,B,256) bf16
__global__ __launch_bounds__(256) void k_conv_x(const float4* __restrict__ x, u16* __restrict__ xb) {
    int idx = blockIdx.x * 256 + threadIdx.x;    // over 64*2048*64 float4s
    float4 v = x[idx];
    int k4 = idx & 63, s = (idx >> 6) & 2047, b = idx >> 17;
    ushort4 o;
    o.x = f2bf(v.x); o.y = f2bf(v.y); o.z = f2bf(v.z); o.w = f2bf(v.w);
    *(ushort4*)(xb + ((s << 6) | b) * 256 + (k4 << 2)) = o;
}

__global__ __launch_bounds__(256) void k_conv_w(const float* __restrict__ W, u16* __restrict__ dst,
                                                int ctot, int c0, int lgc, int n) {
    int i = blockIdx.x * 256 + threadIdx.x;
    if (i >= n) return;
    int r = i >> lgc, c = i & ((1 << lgc) - 1);
    dst[i] = f2bf(W[r * ctot + c0 + c]);
}

// pre[m][n] = sum_k A[m][k]*W[n][k] + bias[n]. A: M x K (M=131072). W: 256 x K.
// grid (1024, 4); block 256. Wave w: m-tiles {bx*128+w*16, +64}, cols n0..n0+63.
// Two M-tiles per wave: W fragments loaded once, used twice.
__global__ __launch_bounds__(256) void k_proj(const u16* __restrict__ A, const u16* __restrict__ W,
                                              const float* __restrict__ bias, u16* __restrict__ out, int K) {
    const int w = threadIdx.x >> 6, ln = threadIdx.x & 63, q = ln >> 4, l = ln & 15;
    const int m0 = blockIdx.x * 128 + w * 16;
    const int n0 = blockIdx.y * 64;
    f32x4 acc[2][4];
#pragma unroll
    for (int g = 0; g < 2; ++g)
#pragma unroll
        for (int u = 0; u < 4; ++u)
#pragma unroll
            for (int r = 0; r < 4; ++r) acc[g][u][r] = 0.0f;
    const u16* Ap0 = A + (size_t)(m0 + l) * K + q * 8;
    const u16* Ap1 = Ap0 + (size_t)64 * K;
    const u16* Wp = W + (size_t)(n0 + l) * K + q * 8;
    const int nch = K >> 5;
    for (int c = 0; c < nch; ++c) {
        short8 a0 = *(const short8*)(Ap0 + c * 32);
        short8 a1 = *(const short8*)(Ap1 + c * 32);
#pragma unroll
        for (int u = 0; u < 4; ++u) {
            short8 bf = *(const short8*)(Wp + u * 16 * K + c * 32);
            acc[0][u] = __builtin_amdgcn_mfma_f32_16x16x32_bf16(a0, bf, acc[0][u], 0, 0, 0);
            acc[1][u] = __builtin_amdgcn_mfma_f32_16x16x32_bf16(a1, bf, acc[1][u], 0, 0, 0);
        }
    }
#pragma unroll
    for (int u = 0; u < 4; ++u) {
        float bia = bias[n0 + u * 16 + l];
#pragma unroll
        for (int g = 0; g < 2; ++g)
#pragma unroll
            for (int r = 0; r < 4; ++r)
                out[(size_t)(m0 + g * 64 + q * 4 + r) * 256 + n0 + u * 16 + l] = f2bf(acc[g][u][r] + bia);
    }
}

// One recurrence step. CUR buffers are compile-time fixed by the caller (loop unrolled x2)
// so prefetch buffers stay in registers. Barrier is raw lgkmcnt-only: the only inter-wave
// data is hbuf (LDS double buffer); pending global loads land in regs, stores are not
// re-read within this kernel.
template <int FINAL>
__device__ __forceinline__ void rnn_step(const ushort4 (&pfC)[4], ushort4 (&pfN)[4],
                                         const u16*& pp, long pstep,
                                         const short8 (&whf)[4][8],
                                         const u16* hcur, u16* hnxt,
                                         int l, int q, int jbase,
                                         u16*& yb, long ybstep, float*& yo, long yostep) {
#pragma unroll
    for (int t = 0; t < 4; ++t) pfN[t] = *(const ushort4*)(pp + t * 16);
    pp += pstep;
    f32x4 acc[4];
#pragma unroll
    for (int t = 0; t < 4; ++t) {
        acc[t][0] = bf2f(pfC[t].x); acc[t][1] = bf2f(pfC[t].y);
        acc[t][2] = bf2f(pfC[t].z); acc[t][3] = bf2f(pfC[t].w);
    }
    short8 hf[8];
#pragma unroll
    for (int c = 0; c < 8; ++c) hf[c] = *(const short8*)(hcur + l * 264 + c * 32 + q * 8);
#pragma unroll
    for (int c = 0; c < 8; ++c) {
#pragma unroll
        for (int t = 0; t < 4; ++t)
            acc[t] = __builtin_amdgcn_mfma_f32_16x16x32_bf16(whf[t][c], hf[c], acc[t], 0, 0, 0);
    }
#pragma unroll
    for (int t = 0; t < 4; ++t) {
        float v0 = fast_tanh(acc[t][0]), v1 = fast_tanh(acc[t][1]);
        float v2 = fast_tanh(acc[t][2]), v3 = fast_tanh(acc[t][3]);
        ushort4 hv;
        hv.x = f2bf(v0); hv.y = f2bf(v1); hv.z = f2bf(v2); hv.w = f2bf(v3);
        *(ushort4*)(hnxt + l * 264 + jbase + t * 16 + q * 4) = hv;
        if (FINAL) {
            *(float4*)(yo + t * 16) = make_float4(v0, v1, v2, v3);
        } else {
            *(ushort4*)(yb + t * 16) = hv;
        }
    }
    if (FINAL) yo += yostep; else yb += ybstep;
    asm volatile("s_waitcnt lgkmcnt(0)\n\ts_barrier" ::: "memory");
}

// grid 8: dir = blk>>2, bc = blk&3 (batch rows bc*16..+15). block 256 (4 waves).
// Wh in register A-fragments (unified VGPR/AGPR file). h via double-buffered LDS
// (stride 264 -> 2-way bank aliasing only, free). pre prefetched 1 step ahead into
// explicit registers; step loop unrolled x2 so no dynamic local indexing exists.
template <int FINAL>
__global__ __launch_bounds__(256, 1) void k_recur(const u16* __restrict__ pre_f, const u16* __restrict__ pre_b,
                                                  const u16* __restrict__ wh_f, const u16* __restrict__ wh_b,
                                                  u16* __restrict__ ybf, float* __restrict__ yf) {
    const int dir = blockIdx.x >> 2, bc = blockIdx.x & 3;
    const int w = threadIdx.x >> 6, ln = threadIdx.x & 63, q = ln >> 4, l = ln & 15;
    const int b0 = bc * 16;
    const u16* pre = dir ? pre_b : pre_f;
    const u16* wh  = dir ? wh_b : wh_f;
    const int coloff = dir * 256;
    const int jbase = w * 64;

    __shared__ __align__(16) u16 hbuf[2][16 * 264];

    short8 whf[4][8];   // Wh A-fragments: Wh[jbase+t*16+l][c*32+q*8 ..+7]
#pragma unroll
    for (int t = 0; t < 4; ++t) {
        const u16* wp = wh + (jbase + t * 16 + l) * 256 + q * 8;
#pragma unroll
        for (int c = 0; c < 8; ++c) whf[t][c] = *(const short8*)(wp + c * 32);
    }
    for (int i = threadIdx.x; i < 16 * 264; i += 256) hbuf[0][i] = 0;  // h_0 = 0
    __syncthreads();

    const int s0 = dir ? (SS - 1) : 0;
    const long sgn = dir ? -1L : 1L;
    const long pstep = sgn * (64 * 256);
    const long ybstep = sgn * (64 * 512);
    const long yostep = sgn * 512;

    const u16* pp = pre + ((size_t)s0 * 64 + b0 + l) * 256 + jbase + q * 4;
    u16* yb = FINAL ? (u16*)nullptr : ybf + ((size_t)s0 * 64 + b0 + l) * 512 + coloff + jbase + q * 4;
    float* yo = FINAL ? yf + ((size_t)(b0 + l) * SS + s0) * 512 + coloff + jbase + q * 4 : (float*)nullptr;

    ushort4 pfA[4], pfB[4];
#pragma unroll
    for (int t = 0; t < 4; ++t) pfA[t] = *(const ushort4*)(pp + t * 16);
    pp += pstep;

    // NOTE: the final iteration's prefetch over/under-runs pre by <=32KB; all such
    // addresses land inside adjacent workspace regions (verified layout), never OOB of d_ws.
    for (int it = 0; it < SS; it += 2) {
        rnn_step<FINAL>(pfA, pfB, pp, pstep, whf, &hbuf[0][0], &hbuf[1][0], l, q, jbase, yb, ybstep, yo, yostep);
        rnn_step<FINAL>(pfB, pfA, pp, pstep, whf, &hbuf[1][0], &hbuf[0][0], l, q, jbase, yb, ybstep, yo, yostep);
    }
}

__global__ __launch_bounds__(256) void k_zero(float* __restrict__ p) {
    p[blockIdx.x * 256 + threadIdx.x] = 0.0f;
}

extern "C" void kernel_launch(void* const* d_in, const int* in_sizes, int n_in,
                              void* d_out, int out_size, void* d_ws, size_t ws_size,
                              hipStream_t stream) {
    const float* x   = (const float*)d_in[0];
    const float* W0f = (const float*)d_in[1];
    const float* b0f = (const float*)d_in[2];
    const float* W0b = (const float*)d_in[3];
    const float* b0b = (const float*)d_in[4];
    const float* W1f = (const float*)d_in[5];
    const float* b1f = (const float*)d_in[6];
    const float* W1b = (const float*)d_in[7];
    const float* b1b = (const float*)d_in[8];
    float* out = (float*)d_out;

    char* ws = (char*)d_ws;
    const size_t MB64 = 64ull << 20;
    u16* xb    = (u16*)(ws);               // 64 MiB; reused later as pre1f
    u16* pre0f = (u16*)(ws + 1 * MB64);    // 64 MiB; reused later as pre1b
    u16* pre0b = (u16*)(ws + 2 * MB64);    // 64 MiB
    u16* y0    = (u16*)(ws + 3 * MB64);    // 128 MiB: y0 (S,B,512) bf16
    u16* wgt   = (u16*)(ws + 5 * MB64);    // ~1.3 MiB converted weights
    u16 *w0fx = wgt,           *w0fh = wgt + 65536,  *w0bx = wgt + 131072, *w0bh = wgt + 196608;
    u16 *w1fx = wgt + 262144,  *w1fh = wgt + 393216, *w1bx = wgt + 458752, *w1bh = wgt + 589824;
    u16* pre1f = xb;
    u16* pre1b = pre0f;

    k_conv_x<<<32768, 256, 0, stream>>>((const float4*)x, xb);
    k_conv_w<<<256, 256, 0, stream>>>(W0f, w0fx, 512, 0,   8, 65536);
    k_conv_w<<<256, 256, 0, stream>>>(W0f, w0fh, 512, 256, 8, 65536);
    k_conv_w<<<256, 256, 0, stream>>>(W0b, w0bx, 512, 0,   8, 65536);
    k_conv_w<<<256, 256, 0, stream>>>(W0b, w0bh, 512, 256, 8, 65536);
    k_conv_w<<<512, 256, 0, stream>>>(W1f, w1fx, 768, 0,   9, 131072);
    k_conv_w<<<256, 256, 0, stream>>>(W1f, w1fh, 768, 512, 8, 65536);
    k_conv_w<<<512, 256, 0, stream>>>(W1b, w1bx, 768, 0,   9, 131072);
    k_conv_w<<<256, 256, 0, stream>>>(W1b, w1bh, 768, 512, 8, 65536);

    dim3 pg(1024, 4);
    k_proj<<<pg, 256, 0, stream>>>(xb, w0fx, b0f, pre0f, 256);
    k_proj<<<pg, 256, 0, stream>>>(xb, w0bx, b0b, pre0b, 256);
    k_recur<0><<<8, 256, 0, stream>>>(pre0f, pre0b, w0fh, w0bh, y0, nullptr);
    k_proj<<<pg, 256, 0, stream>>>(y0, w1fx, b1f, pre1f, 512);
    k_proj<<<pg, 256, 0, stream>>>(y0, w1bx, b1b, pre1b, 512);
    k_recur<1><<<8, 256, 0, stream>>>(pre1f, pre1b, w1fh, w1bh, nullptr, out);
    k_zero<<<256, 256, 0, stream>>>(out + 67108864);  // hn = zeros(4,64,256)
}